// Round 1
// baseline (184.837 us; speedup 1.0000x reference)
//
#include <hip/hip_runtime.h>

#define NV 200000
#define NK 24
#define NCH 64

// ws float offsets
#define PART_OFF 0            // 24*64*3 = 4608
#define J_OFF    4608         // 72
#define ROT_OFF  4680         // 216
#define TR_OFF   4896         // 72
#define PF_OFF   4968         // 216  (total 5184 floats = ~21 KB)

// ---------------- kernel A: v_shaped = v_template + shapedirs . betas --------
__global__ __launch_bounds__(256) void kA(const float* __restrict__ vt,
                                          const float* __restrict__ sd,
                                          const float* __restrict__ betas,
                                          float* __restrict__ vs_out) {
    int v = blockIdx.x * 256 + threadIdx.x;
    if (v >= NV) return;
    float b[10];
#pragma unroll
    for (int i = 0; i < 10; i++) b[i] = betas[i];
    size_t v3 = 3 * (size_t)v;
    float acc0 = vt[v3], acc1 = vt[v3 + 1], acc2 = vt[v3 + 2];
    const float2* s2 = (const float2*)(sd) + (size_t)v * 15;
#pragma unroll
    for (int j = 0; j < 15; j++) {
        float2 s = s2[j];
        const int e0 = 2 * j, e1 = 2 * j + 1;
        float p0 = s.x * b[e0 % 10];
        float p1 = s.y * b[e1 % 10];
        if (e0 / 10 == 0) acc0 += p0; else if (e0 / 10 == 1) acc1 += p0; else acc2 += p0;
        if (e1 / 10 == 0) acc0 += p1; else if (e1 / 10 == 1) acc1 += p1; else acc2 += p1;
    }
    vs_out[v3] = acc0; vs_out[v3 + 1] = acc1; vs_out[v3 + 2] = acc2;
}

// ---------------- kernel B: per-(k,chunk) partial sums of J_regressor @ vs ---
__global__ __launch_bounds__(256) void kB(const float* __restrict__ jr,
                                          const float* __restrict__ vs,
                                          float* __restrict__ ws) {
    int k = blockIdx.x >> 6;        // /NCH
    int chunk = blockIdx.x & 63;
    const float* row = jr + (size_t)k * NV;
    float a0 = 0.f, a1 = 0.f, a2 = 0.f;
    for (int v = chunk * 256 + threadIdx.x; v < NV; v += NCH * 256) {
        float w = row[v];
        size_t v3 = 3 * (size_t)v;
        a0 = fmaf(w, vs[v3], a0);
        a1 = fmaf(w, vs[v3 + 1], a1);
        a2 = fmaf(w, vs[v3 + 2], a2);
    }
#pragma unroll
    for (int off = 32; off; off >>= 1) {
        a0 += __shfl_xor(a0, off, 64);
        a1 += __shfl_xor(a1, off, 64);
        a2 += __shfl_xor(a2, off, 64);
    }
    __shared__ float red[4][3];
    int lane = threadIdx.x & 63, wv = threadIdx.x >> 6;
    if (lane == 0) { red[wv][0] = a0; red[wv][1] = a1; red[wv][2] = a2; }
    __syncthreads();
    if (threadIdx.x < 3) {
        float s = red[0][threadIdx.x] + red[1][threadIdx.x] +
                  red[2][threadIdx.x] + red[3][threadIdx.x];
        ws[PART_OFF + blockIdx.x * 3 + threadIdx.x] = s;
    }
}

// ---------------- kernel C: J reduce, Rodrigues, kinematic chain -------------
__global__ __launch_bounds__(128) void kC(const float* __restrict__ pose,
                                          float* __restrict__ ws) {
    __shared__ float Jl[72];
    __shared__ float Rl[24][9];
    __shared__ float Ar[24][9];
    __shared__ float At[24][3];
    int t = threadIdx.x;
    if (t < 72) {
        int k = t / 3, c = t % 3;
        float s = 0.f;
        for (int ch = 0; ch < NCH; ch++) s += ws[PART_OFF + (k * NCH + ch) * 3 + c];
        Jl[t] = s;
        ws[J_OFF + t] = s;
    }
    if (t < 24) {
        float rx = pose[3 * t], ry = pose[3 * t + 1], rz = pose[3 * t + 2];
        float tx = rx + 1e-12f, ty = ry + 1e-12f, tz = rz + 1e-12f;
        float th = sqrtf(tx * tx + ty * ty + tz * tz);
        float inv = 1.0f / th;
        float kx = rx * inv, ky = ry * inv, kz = rz * inv;
        float s = sinf(th), c = cosf(th), oc = 1.0f - c;
        float R00 = 1.f + oc * (-(ky * ky + kz * kz));
        float R01 = -s * kz + oc * kx * ky;
        float R02 =  s * ky + oc * kx * kz;
        float R10 =  s * kz + oc * kx * ky;
        float R11 = 1.f + oc * (-(kx * kx + kz * kz));
        float R12 = -s * kx + oc * ky * kz;
        float R20 = -s * ky + oc * kx * kz;
        float R21 =  s * kx + oc * ky * kz;
        float R22 = 1.f + oc * (-(kx * kx + ky * ky));
        Rl[t][0] = R00; Rl[t][1] = R01; Rl[t][2] = R02;
        Rl[t][3] = R10; Rl[t][4] = R11; Rl[t][5] = R12;
        Rl[t][6] = R20; Rl[t][7] = R21; Rl[t][8] = R22;
        float* pf = ws + PF_OFF + t * 9;
        pf[0] = R00 - 1.f; pf[1] = R01;       pf[2] = R02;
        pf[3] = R10;       pf[4] = R11 - 1.f; pf[5] = R12;
        pf[6] = R20;       pf[7] = R21;       pf[8] = R22 - 1.f;
    }
    __syncthreads();
    if (t == 0) {
        const int par[24] = {0,0,0,0,1,2,3,4,5,6,7,8,9,9,9,12,13,14,16,17,18,19,20,21};
        for (int e = 0; e < 9; e++) Ar[0][e] = Rl[0][e];
        At[0][0] = Jl[0]; At[0][1] = Jl[1]; At[0][2] = Jl[2];
        for (int j = 1; j < 24; j++) {
            int p = par[j];
            float rel0 = Jl[3 * j] - Jl[3 * p];
            float rel1 = Jl[3 * j + 1] - Jl[3 * p + 1];
            float rel2 = Jl[3 * j + 2] - Jl[3 * p + 2];
            for (int i = 0; i < 3; i++) {
                float ai0 = Ar[p][i * 3], ai1 = Ar[p][i * 3 + 1], ai2 = Ar[p][i * 3 + 2];
                for (int jj = 0; jj < 3; jj++) {
                    Ar[j][i * 3 + jj] = ai0 * Rl[j][jj] + ai1 * Rl[j][3 + jj] + ai2 * Rl[j][6 + jj];
                }
                At[j][i] = ai0 * rel0 + ai1 * rel1 + ai2 * rel2 + At[p][i];
            }
        }
        for (int k = 0; k < 24; k++) {
            for (int i = 0; i < 3; i++) {
                float tr = At[k][i] - (Ar[k][i * 3] * Jl[3 * k] +
                                       Ar[k][i * 3 + 1] * Jl[3 * k + 1] +
                                       Ar[k][i * 3 + 2] * Jl[3 * k + 2]);
                ws[TR_OFF + k * 3 + i] = tr;
            }
            for (int e = 0; e < 9; e++) ws[ROT_OFF + k * 9 + e] = Ar[k][e];
        }
    }
}

// ---------------- kernel D: wave-per-vertex posedirs dot + skinning ----------
__global__ __launch_bounds__(256) void kD(const float* __restrict__ pd,
                                          const float* __restrict__ wts,
                                          const float* __restrict__ ws,
                                          float* __restrict__ out) {
    __shared__ float4 pfr[162];   // pose_feat replicated 3x (648 floats)
    __shared__ float rotS[216];
    __shared__ float trS[72];
    int t = threadIdx.x;
    float* pfrF = (float*)pfr;
    for (int i = t; i < 648; i += 256) pfrF[i] = ws[PF_OFF + (i % 216)];
    if (t < 216) rotS[t] = ws[ROT_OFF + t];
    if (t < 72)  trS[t]  = ws[TR_OFF + t];
    __syncthreads();

    int lane = t & 63;
    int wid = (blockIdx.x << 2) + (t >> 6);
    int stride = gridDim.x << 2;
    for (int v = wid; v < NV; v += stride) {
        const float4* p4 = (const float4*)(pd) + (size_t)v * 162;
        float4 a0v = p4[lane];       float4 b0v = pfr[lane];
        float4 a1v = p4[lane + 64];  float4 b1v = pfr[lane + 64];
        float d0 = a0v.x * b0v.x + a0v.y * b0v.y + a0v.z * b0v.z + a0v.w * b0v.w;
        float d1 = a1v.x * b1v.x + a1v.y * b1v.y + a1v.z * b1v.z + a1v.w * b1v.w;
        // float4 index i: c = i/54.  i=lane: c0 iff lane<54.  i=lane+64: c1 iff lane<44.
        float s0 = (lane < 54) ? d0 : 0.f;
        float s1 = ((lane < 54) ? 0.f : d0) + ((lane < 44) ? d1 : 0.f);
        float s2 = (lane < 44) ? 0.f : d1;
        if (lane < 34) {  // i = lane+128 in [128,162): all c==2
            float4 a2v = p4[lane + 128]; float4 b2v = pfr[lane + 128];
            s2 += a2v.x * b2v.x + a2v.y * b2v.y + a2v.z * b2v.z + a2v.w * b2v.w;
        }
#pragma unroll
        for (int off = 32; off; off >>= 1) {
            s0 += __shfl_xor(s0, off, 64);
            s1 += __shfl_xor(s1, off, 64);
            s2 += __shfl_xor(s2, off, 64);
        }
        if (lane < 3) {
            size_t v3 = 3 * (size_t)v;
            float vp0 = out[v3]     + s0;   // out currently holds v_shaped
            float vp1 = out[v3 + 1] + s1;
            float vp2 = out[v3 + 2] + s2;
            const float* w = wts + (size_t)v * 24;
            float o = 0.f;
#pragma unroll
            for (int k = 0; k < 24; k++) {
                float m = rotS[k * 9 + lane * 3] * vp0 +
                          rotS[k * 9 + lane * 3 + 1] * vp1 +
                          rotS[k * 9 + lane * 3 + 2] * vp2 +
                          trS[k * 3 + lane];
                o = fmaf(w[k], m, o);
            }
            out[v3 + lane] = o;
        }
    }
}

extern "C" void kernel_launch(void* const* d_in, const int* in_sizes, int n_in,
                              void* d_out, int out_size, void* d_ws, size_t ws_size,
                              hipStream_t stream) {
    const float* betas = (const float*)d_in[0];
    const float* pose  = (const float*)d_in[1];
    const float* vt    = (const float*)d_in[2];
    const float* sd    = (const float*)d_in[3];
    const float* pd    = (const float*)d_in[4];
    const float* jr    = (const float*)d_in[5];
    const float* wts   = (const float*)d_in[6];
    float* out = (float*)d_out;
    float* ws  = (float*)d_ws;

    kA<<<(NV + 255) / 256, 256, 0, stream>>>(vt, sd, betas, out);
    kB<<<NK * NCH, 256, 0, stream>>>(jr, out, ws);
    kC<<<1, 128, 0, stream>>>(pose, ws);
    kD<<<2048, 256, 0, stream>>>(pd, wts, ws, out);
}

// Round 2
// 132.058 us; speedup vs baseline: 1.3997x; 1.3997x over previous
//
#include <hip/hip_runtime.h>

#define NV 200000
#define NK 24
#define NCH 64

// ws float offsets
#define PART_OFF 0            // 24*64*3 = 4608
#define J_OFF    4608         // 72
#define ROT_OFF  4680         // 216
#define TR_OFF   4896         // 72
#define PF_OFF   4968         // 216  (total 5184 floats = ~21 KB)

// ---------------- kernel A: v_shaped = v_template + shapedirs . betas --------
__global__ __launch_bounds__(256) void kA(const float* __restrict__ vt,
                                          const float* __restrict__ sd,
                                          const float* __restrict__ betas,
                                          float* __restrict__ vs_out) {
    int v = blockIdx.x * 256 + threadIdx.x;
    if (v >= NV) return;
    float b[10];
#pragma unroll
    for (int i = 0; i < 10; i++) b[i] = betas[i];
    size_t v3 = 3 * (size_t)v;
    float acc0 = vt[v3], acc1 = vt[v3 + 1], acc2 = vt[v3 + 2];
    const float2* s2 = (const float2*)(sd) + (size_t)v * 15;
#pragma unroll
    for (int j = 0; j < 15; j++) {
        float2 s = s2[j];
        const int e0 = 2 * j, e1 = 2 * j + 1;
        float p0 = s.x * b[e0 % 10];
        float p1 = s.y * b[e1 % 10];
        if (e0 / 10 == 0) acc0 += p0; else if (e0 / 10 == 1) acc1 += p0; else acc2 += p0;
        if (e1 / 10 == 0) acc0 += p1; else if (e1 / 10 == 1) acc1 += p1; else acc2 += p1;
    }
    vs_out[v3] = acc0; vs_out[v3 + 1] = acc1; vs_out[v3 + 2] = acc2;
}

// ---------------- kernel B: per-(k,chunk) partial sums of J_regressor @ vs ---
__global__ __launch_bounds__(256) void kB(const float* __restrict__ jr,
                                          const float* __restrict__ vs,
                                          float* __restrict__ ws) {
    int k = blockIdx.x >> 6;        // /NCH
    int chunk = blockIdx.x & 63;
    const float* row = jr + (size_t)k * NV;
    float a0 = 0.f, a1 = 0.f, a2 = 0.f;
    for (int v = chunk * 256 + threadIdx.x; v < NV; v += NCH * 256) {
        float w = row[v];
        size_t v3 = 3 * (size_t)v;
        a0 = fmaf(w, vs[v3], a0);
        a1 = fmaf(w, vs[v3 + 1], a1);
        a2 = fmaf(w, vs[v3 + 2], a2);
    }
#pragma unroll
    for (int off = 32; off; off >>= 1) {
        a0 += __shfl_xor(a0, off, 64);
        a1 += __shfl_xor(a1, off, 64);
        a2 += __shfl_xor(a2, off, 64);
    }
    __shared__ float red[4][3];
    int lane = threadIdx.x & 63, wv = threadIdx.x >> 6;
    if (lane == 0) { red[wv][0] = a0; red[wv][1] = a1; red[wv][2] = a2; }
    __syncthreads();
    if (threadIdx.x < 3) {
        float s = red[0][threadIdx.x] + red[1][threadIdx.x] +
                  red[2][threadIdx.x] + red[3][threadIdx.x];
        ws[PART_OFF + blockIdx.x * 3 + threadIdx.x] = s;
    }
}

// ---------------- kernel C: J reduce, Rodrigues, depth-parallel chain --------
__global__ __launch_bounds__(64) void kC(const float* __restrict__ pose,
                                         float* __restrict__ ws) {
    __shared__ float Jl[72];
    __shared__ float Rl[24][9];
    __shared__ float Ar[24][9];
    __shared__ float At[24][3];
    int t = threadIdx.x;

    // J reduce: (k,c) pairs over 64 chunks
    for (int idx = t; idx < 72; idx += 64) {
        int k = idx / 3, c = idx % 3;
        float s = 0.f;
#pragma unroll
        for (int ch = 0; ch < NCH; ch++) s += ws[PART_OFF + (k * NCH + ch) * 3 + c];
        Jl[idx] = s;
    }

    if (t < 24) {
        float rx = pose[3 * t], ry = pose[3 * t + 1], rz = pose[3 * t + 2];
        float tx = rx + 1e-12f, ty = ry + 1e-12f, tz = rz + 1e-12f;
        float th = sqrtf(tx * tx + ty * ty + tz * tz);
        float inv = 1.0f / th;
        float kx = rx * inv, ky = ry * inv, kz = rz * inv;
        float s = sinf(th), c = cosf(th), oc = 1.0f - c;
        float R00 = 1.f + oc * (-(ky * ky + kz * kz));
        float R01 = -s * kz + oc * kx * ky;
        float R02 =  s * ky + oc * kx * kz;
        float R10 =  s * kz + oc * kx * ky;
        float R11 = 1.f + oc * (-(kx * kx + kz * kz));
        float R12 = -s * kx + oc * ky * kz;
        float R20 = -s * ky + oc * kx * kz;
        float R21 =  s * kx + oc * ky * kz;
        float R22 = 1.f + oc * (-(kx * kx + ky * ky));
        Rl[t][0] = R00; Rl[t][1] = R01; Rl[t][2] = R02;
        Rl[t][3] = R10; Rl[t][4] = R11; Rl[t][5] = R12;
        Rl[t][6] = R20; Rl[t][7] = R21; Rl[t][8] = R22;
        float* pf = ws + PF_OFF + t * 9;
        pf[0] = R00 - 1.f; pf[1] = R01;       pf[2] = R02;
        pf[3] = R10;       pf[4] = R11 - 1.f; pf[5] = R12;
        pf[6] = R20;       pf[7] = R21;       pf[8] = R22 - 1.f;
    }
    __syncthreads();

    const int par[24] = {0,0,0,0,1,2,3,4,5,6,7,8,9,9,9,12,13,14,16,17,18,19,20,21};
    const int lvl[24] = {0,1,1,1,2,2,2,3,3,3,4,4,4,4,4,5,5,5,6,6,7,7,8,8};
    float rel0 = 0.f, rel1 = 0.f, rel2 = 0.f;
    int p = 0, myl = -1;
    if (t < 24) {
        p = par[t]; myl = lvl[t];
        if (t == 0) { rel0 = Jl[0]; rel1 = Jl[1]; rel2 = Jl[2]; }
        else {
            rel0 = Jl[3 * t]     - Jl[3 * p];
            rel1 = Jl[3 * t + 1] - Jl[3 * p + 1];
            rel2 = Jl[3 * t + 2] - Jl[3 * p + 2];
        }
    }
    for (int L = 0; L < 9; L++) {
        if (myl == L) {
            if (t == 0) {
#pragma unroll
                for (int e = 0; e < 9; e++) Ar[0][e] = Rl[0][e];
                At[0][0] = rel0; At[0][1] = rel1; At[0][2] = rel2;
            } else {
#pragma unroll
                for (int i = 0; i < 3; i++) {
                    float ai0 = Ar[p][i * 3], ai1 = Ar[p][i * 3 + 1], ai2 = Ar[p][i * 3 + 2];
#pragma unroll
                    for (int jj = 0; jj < 3; jj++) {
                        Ar[t][i * 3 + jj] = ai0 * Rl[t][jj] + ai1 * Rl[t][3 + jj] + ai2 * Rl[t][6 + jj];
                    }
                    At[t][i] = ai0 * rel0 + ai1 * rel1 + ai2 * rel2 + At[p][i];
                }
            }
        }
        __syncthreads();
    }
    if (t < 24) {
#pragma unroll
        for (int i = 0; i < 3; i++) {
            float tr = At[t][i] - (Ar[t][i * 3]     * Jl[3 * t] +
                                   Ar[t][i * 3 + 1] * Jl[3 * t + 1] +
                                   Ar[t][i * 3 + 2] * Jl[3 * t + 2]);
            ws[TR_OFF + t * 3 + i] = tr;
        }
#pragma unroll
        for (int e = 0; e < 9; e++) ws[ROT_OFF + t * 9 + e] = Ar[t][e];
    }
}

// ---------------- kernel D: wave-per-vertex posedirs dot + lane-parallel skin
__global__ __launch_bounds__(256) void kD(const float* __restrict__ pd,
                                          const float* __restrict__ wts,
                                          const float* __restrict__ ws,
                                          float* __restrict__ out) {
    int t = threadIdx.x;
    int lane = t & 63;

    // pose_feat fragments, hoisted to registers (pf replicated per channel:
    // pf4rep[i] = pf4[i % 54], since 216 % 4 == 0)
    const float4* pf4 = (const float4*)(ws + PF_OFF);   // 54 float4
    float4 b0 = pf4[lane % 54];
    float4 b1 = pf4[(lane + 64) % 54];
    float4 b2 = pf4[(lane + 128) % 54];

    // per-lane joint registers: lane (kk = lane&31) owns joint kk if kk<24
    int kk = lane & 31;
    float rr0=0,rr1=0,rr2=0,rr3=0,rr4=0,rr5=0,rr6=0,rr7=0,rr8=0;
    float tt0=0, tt1=0, tt2=0;
    if (kk < 24) {
        const float* r = ws + ROT_OFF + kk * 9;
        rr0=r[0]; rr1=r[1]; rr2=r[2]; rr3=r[3]; rr4=r[4];
        rr5=r[5]; rr6=r[6]; rr7=r[7]; rr8=r[8];
        const float* tr = ws + TR_OFF + kk * 3;
        tt0=tr[0]; tt1=tr[1]; tt2=tr[2];
    }

    int wid = (blockIdx.x << 2) + (t >> 6);
    int stride = gridDim.x << 2;
    for (int v = wid; v < NV; v += stride) {
        const float4* p4 = (const float4*)(pd) + (size_t)v * 162;
        float4 a0 = p4[lane];
        float4 a1 = p4[lane + 64];
        float d2 = 0.f;
        if (lane < 34) {
            float4 a2 = p4[lane + 128];
            d2 = a2.x * b2.x + a2.y * b2.y + a2.z * b2.z + a2.w * b2.w;
        }
        size_t v3 = 3 * (size_t)v;
        float vs0 = out[v3], vs1 = out[v3 + 1], vs2 = out[v3 + 2];
        float wk = (kk < 24) ? wts[(size_t)v * 24 + kk] : 0.f;

        float d0 = a0.x * b0.x + a0.y * b0.y + a0.z * b0.z + a0.w * b0.w;
        float d1 = a1.x * b1.x + a1.y * b1.y + a1.z * b1.z + a1.w * b1.w;
        // channel boundaries at float4 indices 54 and 108
        float s0 = (lane < 54) ? d0 : 0.f;
        float s1 = ((lane < 54) ? 0.f : d0) + ((lane < 44) ? d1 : 0.f);
        float s2 = ((lane < 44) ? 0.f : d1) + d2;
#pragma unroll
        for (int off = 32; off; off >>= 1) {
            s0 += __shfl_xor(s0, off, 64);
            s1 += __shfl_xor(s1, off, 64);
            s2 += __shfl_xor(s2, off, 64);
        }
        float vp0 = vs0 + s0, vp1 = vs1 + s1, vp2 = vs2 + s2;
        float m0 = wk * (rr0 * vp0 + rr1 * vp1 + rr2 * vp2 + tt0);
        float m1 = wk * (rr3 * vp0 + rr4 * vp1 + rr5 * vp2 + tt1);
        float m2 = wk * (rr6 * vp0 + rr7 * vp1 + rr8 * vp2 + tt2);
#pragma unroll
        for (int off = 16; off; off >>= 1) {
            m0 += __shfl_xor(m0, off, 64);
            m1 += __shfl_xor(m1, off, 64);
            m2 += __shfl_xor(m2, off, 64);
        }
        if (lane < 3) {
            out[v3 + lane] = (lane == 0) ? m0 : (lane == 1) ? m1 : m2;
        }
    }
}

extern "C" void kernel_launch(void* const* d_in, const int* in_sizes, int n_in,
                              void* d_out, int out_size, void* d_ws, size_t ws_size,
                              hipStream_t stream) {
    const float* betas = (const float*)d_in[0];
    const float* pose  = (const float*)d_in[1];
    const float* vt    = (const float*)d_in[2];
    const float* sd    = (const float*)d_in[3];
    const float* pd    = (const float*)d_in[4];
    const float* jr    = (const float*)d_in[5];
    const float* wts   = (const float*)d_in[6];
    float* out = (float*)d_out;
    float* ws  = (float*)d_ws;

    kA<<<(NV + 255) / 256, 256, 0, stream>>>(vt, sd, betas, out);
    kB<<<NK * NCH, 256, 0, stream>>>(jr, out, ws);
    kC<<<1, 64, 0, stream>>>(pose, ws);
    kD<<<2048, 256, 0, stream>>>(pd, wts, ws, out);
}

// Round 3
// 127.872 us; speedup vs baseline: 1.4455x; 1.0327x over previous
//
#include <hip/hip_runtime.h>

#define NV 200000
#define NK 24
#define NCH 64

// ws float offsets
#define PART_OFF 0            // 24*64*3 = 4608
#define J_OFF    4608         // 72
#define ROT_OFF  4680         // 216
#define TR_OFF   4896         // 72
#define PF_OFF   4968         // 216  (total 5184 floats = ~21 KB)

// DPP butterfly add: x += lane_permuted(x). All-VALU, no DS pipe.
// 0xB1 = quad_perm [1,0,3,2] (xor1)   0x4E = quad_perm [2,3,0,1] (xor2)
// 0x141 = row_half_mirror (acts as xor4 once quads are uniform)
// 0x140 = row_mirror      (acts as xor8 once octets are uniform)
template <int CTRL>
__device__ __forceinline__ float dpp_add(float x) {
    int y = __builtin_amdgcn_update_dpp(0, __float_as_int(x), CTRL, 0xf, 0xf, true);
    return x + __int_as_float(y);
}

// ---------------- kernel A: v_shaped = v_template + shapedirs . betas --------
__global__ __launch_bounds__(256) void kA(const float* __restrict__ vt,
                                          const float* __restrict__ sd,
                                          const float* __restrict__ betas,
                                          float* __restrict__ vs_out) {
    int v = blockIdx.x * 256 + threadIdx.x;
    if (v >= NV) return;
    float b[10];
#pragma unroll
    for (int i = 0; i < 10; i++) b[i] = betas[i];
    size_t v3 = 3 * (size_t)v;
    float acc0 = vt[v3], acc1 = vt[v3 + 1], acc2 = vt[v3 + 2];
    const float2* s2 = (const float2*)(sd) + (size_t)v * 15;
#pragma unroll
    for (int j = 0; j < 15; j++) {
        float2 s = s2[j];
        const int e0 = 2 * j, e1 = 2 * j + 1;
        float p0 = s.x * b[e0 % 10];
        float p1 = s.y * b[e1 % 10];
        if (e0 / 10 == 0) acc0 += p0; else if (e0 / 10 == 1) acc1 += p0; else acc2 += p0;
        if (e1 / 10 == 0) acc0 += p1; else if (e1 / 10 == 1) acc1 += p1; else acc2 += p1;
    }
    vs_out[v3] = acc0; vs_out[v3 + 1] = acc1; vs_out[v3 + 2] = acc2;
}

// ---------------- kernel B: per-(k,chunk) partial sums of J_regressor @ vs ---
__global__ __launch_bounds__(256) void kB(const float* __restrict__ jr,
                                          const float* __restrict__ vs,
                                          float* __restrict__ ws) {
    int k = blockIdx.x >> 6;        // /NCH
    int chunk = blockIdx.x & 63;
    const float* row = jr + (size_t)k * NV;
    float a0 = 0.f, a1 = 0.f, a2 = 0.f;
    for (int v = chunk * 256 + threadIdx.x; v < NV; v += NCH * 256) {
        float w = row[v];
        size_t v3 = 3 * (size_t)v;
        a0 = fmaf(w, vs[v3], a0);
        a1 = fmaf(w, vs[v3 + 1], a1);
        a2 = fmaf(w, vs[v3 + 2], a2);
    }
#pragma unroll
    for (int off = 32; off; off >>= 1) {
        a0 += __shfl_xor(a0, off, 64);
        a1 += __shfl_xor(a1, off, 64);
        a2 += __shfl_xor(a2, off, 64);
    }
    __shared__ float red[4][3];
    int lane = threadIdx.x & 63, wv = threadIdx.x >> 6;
    if (lane == 0) { red[wv][0] = a0; red[wv][1] = a1; red[wv][2] = a2; }
    __syncthreads();
    if (threadIdx.x < 3) {
        float s = red[0][threadIdx.x] + red[1][threadIdx.x] +
                  red[2][threadIdx.x] + red[3][threadIdx.x];
        ws[PART_OFF + blockIdx.x * 3 + threadIdx.x] = s;
    }
}

// ---------------- kernel C: J reduce, Rodrigues, depth-parallel chain --------
__global__ __launch_bounds__(64) void kC(const float* __restrict__ pose,
                                         float* __restrict__ ws) {
    __shared__ float Jl[72];
    __shared__ float Rl[24][9];
    __shared__ float Ar[24][9];
    __shared__ float At[24][3];
    int t = threadIdx.x;

    for (int idx = t; idx < 72; idx += 64) {
        int k = idx / 3, c = idx % 3;
        float s = 0.f;
#pragma unroll
        for (int ch = 0; ch < NCH; ch++) s += ws[PART_OFF + (k * NCH + ch) * 3 + c];
        Jl[idx] = s;
    }

    if (t < 24) {
        float rx = pose[3 * t], ry = pose[3 * t + 1], rz = pose[3 * t + 2];
        float tx = rx + 1e-12f, ty = ry + 1e-12f, tz = rz + 1e-12f;
        float th = sqrtf(tx * tx + ty * ty + tz * tz);
        float inv = 1.0f / th;
        float kx = rx * inv, ky = ry * inv, kz = rz * inv;
        float s = sinf(th), c = cosf(th), oc = 1.0f - c;
        float R00 = 1.f + oc * (-(ky * ky + kz * kz));
        float R01 = -s * kz + oc * kx * ky;
        float R02 =  s * ky + oc * kx * kz;
        float R10 =  s * kz + oc * kx * ky;
        float R11 = 1.f + oc * (-(kx * kx + kz * kz));
        float R12 = -s * kx + oc * ky * kz;
        float R20 = -s * ky + oc * kx * kz;
        float R21 =  s * kx + oc * ky * kz;
        float R22 = 1.f + oc * (-(kx * kx + ky * ky));
        Rl[t][0] = R00; Rl[t][1] = R01; Rl[t][2] = R02;
        Rl[t][3] = R10; Rl[t][4] = R11; Rl[t][5] = R12;
        Rl[t][6] = R20; Rl[t][7] = R21; Rl[t][8] = R22;
        float* pf = ws + PF_OFF + t * 9;
        pf[0] = R00 - 1.f; pf[1] = R01;       pf[2] = R02;
        pf[3] = R10;       pf[4] = R11 - 1.f; pf[5] = R12;
        pf[6] = R20;       pf[7] = R21;       pf[8] = R22 - 1.f;
    }
    __syncthreads();

    const int par[24] = {0,0,0,0,1,2,3,4,5,6,7,8,9,9,9,12,13,14,16,17,18,19,20,21};
    const int lvl[24] = {0,1,1,1,2,2,2,3,3,3,4,4,4,4,4,5,5,5,6,6,7,7,8,8};
    float rel0 = 0.f, rel1 = 0.f, rel2 = 0.f;
    int p = 0, myl = -1;
    if (t < 24) {
        p = par[t]; myl = lvl[t];
        if (t == 0) { rel0 = Jl[0]; rel1 = Jl[1]; rel2 = Jl[2]; }
        else {
            rel0 = Jl[3 * t]     - Jl[3 * p];
            rel1 = Jl[3 * t + 1] - Jl[3 * p + 1];
            rel2 = Jl[3 * t + 2] - Jl[3 * p + 2];
        }
    }
    for (int L = 0; L < 9; L++) {
        if (myl == L) {
            if (t == 0) {
#pragma unroll
                for (int e = 0; e < 9; e++) Ar[0][e] = Rl[0][e];
                At[0][0] = rel0; At[0][1] = rel1; At[0][2] = rel2;
            } else {
#pragma unroll
                for (int i = 0; i < 3; i++) {
                    float ai0 = Ar[p][i * 3], ai1 = Ar[p][i * 3 + 1], ai2 = Ar[p][i * 3 + 2];
#pragma unroll
                    for (int jj = 0; jj < 3; jj++) {
                        Ar[t][i * 3 + jj] = ai0 * Rl[t][jj] + ai1 * Rl[t][3 + jj] + ai2 * Rl[t][6 + jj];
                    }
                    At[t][i] = ai0 * rel0 + ai1 * rel1 + ai2 * rel2 + At[p][i];
                }
            }
        }
        __syncthreads();
    }
    if (t < 24) {
#pragma unroll
        for (int i = 0; i < 3; i++) {
            float tr = At[t][i] - (Ar[t][i * 3]     * Jl[3 * t] +
                                   Ar[t][i * 3 + 1] * Jl[3 * t + 1] +
                                   Ar[t][i * 3 + 2] * Jl[3 * t + 2]);
            ws[TR_OFF + t * 3 + i] = tr;
        }
#pragma unroll
        for (int e = 0; e < 9; e++) ws[ROT_OFF + t * 9 + e] = Ar[t][e];
    }
}

// ---------------- kernel D: wave-per-vertex posedirs dot + lane-parallel skin
__global__ __launch_bounds__(256) void kD(const float* __restrict__ pd,
                                          const float* __restrict__ wts,
                                          const float* __restrict__ ws,
                                          float* __restrict__ out) {
    int t = threadIdx.x;
    int lane = t & 63;

    const float4* pf4 = (const float4*)(ws + PF_OFF);   // 54 float4
    float4 b0 = pf4[lane % 54];
    float4 b1 = pf4[(lane + 64) % 54];
    float4 b2 = pf4[(lane + 128) % 54];

    // per-lane joint registers: lane (kk = lane&31) owns joint kk if kk<24
    int kk = lane & 31;
    float rr0=0,rr1=0,rr2=0,rr3=0,rr4=0,rr5=0,rr6=0,rr7=0,rr8=0;
    float tt0=0, tt1=0, tt2=0;
    if (kk < 24) {
        const float* r = ws + ROT_OFF + kk * 9;
        rr0=r[0]; rr1=r[1]; rr2=r[2]; rr3=r[3]; rr4=r[4];
        rr5=r[5]; rr6=r[6]; rr7=r[7]; rr8=r[8];
        const float* tr = ws + TR_OFF + kk * 3;
        tt0=tr[0]; tt1=tr[1]; tt2=tr[2];
    }

    int wid = (blockIdx.x << 2) + (t >> 6);
    int stride = gridDim.x << 2;
    for (int v = wid; v < NV; v += stride) {
        const float4* p4 = (const float4*)(pd) + (size_t)v * 162;
        float4 a0 = p4[lane];
        float4 a1 = p4[lane + 64];
        float d2 = 0.f;
        if (lane < 34) {
            float4 a2 = p4[lane + 128];
            d2 = a2.x * b2.x + a2.y * b2.y + a2.z * b2.z + a2.w * b2.w;
        }
        size_t v3 = 3 * (size_t)v;
        float vs0 = out[v3], vs1 = out[v3 + 1], vs2 = out[v3 + 2];
        float wk = (kk < 24) ? wts[(size_t)v * 24 + kk] : 0.f;

        float d0 = a0.x * b0.x + a0.y * b0.y + a0.z * b0.z + a0.w * b0.w;
        float d1 = a1.x * b1.x + a1.y * b1.y + a1.z * b1.z + a1.w * b1.w;
        // channel boundaries at float4 indices 54 and 108
        float s0 = (lane < 54) ? d0 : 0.f;
        float s1 = ((lane < 54) ? 0.f : d0) + ((lane < 44) ? d1 : 0.f);
        float s2 = ((lane < 44) ? 0.f : d1) + d2;

        // 64-lane all-reduce: 4 DPP levels (VALU) + 2 shuffle crossings (DS)
        s0 = dpp_add<0xB1>(s0); s1 = dpp_add<0xB1>(s1); s2 = dpp_add<0xB1>(s2);
        s0 = dpp_add<0x4E>(s0); s1 = dpp_add<0x4E>(s1); s2 = dpp_add<0x4E>(s2);
        s0 = dpp_add<0x141>(s0); s1 = dpp_add<0x141>(s1); s2 = dpp_add<0x141>(s2);
        s0 = dpp_add<0x140>(s0); s1 = dpp_add<0x140>(s1); s2 = dpp_add<0x140>(s2);
        s0 += __shfl_xor(s0, 16, 64); s1 += __shfl_xor(s1, 16, 64); s2 += __shfl_xor(s2, 16, 64);
        s0 += __shfl_xor(s0, 32, 64); s1 += __shfl_xor(s1, 32, 64); s2 += __shfl_xor(s2, 32, 64);

        float vp0 = vs0 + s0, vp1 = vs1 + s1, vp2 = vs2 + s2;
        float m0 = wk * (rr0 * vp0 + rr1 * vp1 + rr2 * vp2 + tt0);
        float m1 = wk * (rr3 * vp0 + rr4 * vp1 + rr5 * vp2 + tt1);
        float m2 = wk * (rr6 * vp0 + rr7 * vp1 + rr8 * vp2 + tt2);

        // 32-lane reduce (halves are duplicates): 4 DPP + 1 shuffle
        m0 = dpp_add<0xB1>(m0); m1 = dpp_add<0xB1>(m1); m2 = dpp_add<0xB1>(m2);
        m0 = dpp_add<0x4E>(m0); m1 = dpp_add<0x4E>(m1); m2 = dpp_add<0x4E>(m2);
        m0 = dpp_add<0x141>(m0); m1 = dpp_add<0x141>(m1); m2 = dpp_add<0x141>(m2);
        m0 = dpp_add<0x140>(m0); m1 = dpp_add<0x140>(m1); m2 = dpp_add<0x140>(m2);
        m0 += __shfl_xor(m0, 16, 64); m1 += __shfl_xor(m1, 16, 64); m2 += __shfl_xor(m2, 16, 64);

        if (lane < 3) {
            out[v3 + lane] = (lane == 0) ? m0 : (lane == 1) ? m1 : m2;
        }
    }
}

extern "C" void kernel_launch(void* const* d_in, const int* in_sizes, int n_in,
                              void* d_out, int out_size, void* d_ws, size_t ws_size,
                              hipStream_t stream) {
    const float* betas = (const float*)d_in[0];
    const float* pose  = (const float*)d_in[1];
    const float* vt    = (const float*)d_in[2];
    const float* sd    = (const float*)d_in[3];
    const float* pd    = (const float*)d_in[4];
    const float* jr    = (const float*)d_in[5];
    const float* wts   = (const float*)d_in[6];
    float* out = (float*)d_out;
    float* ws  = (float*)d_ws;

    kA<<<(NV + 255) / 256, 256, 0, stream>>>(vt, sd, betas, out);
    kB<<<NK * NCH, 256, 0, stream>>>(jr, out, ws);
    kC<<<1, 64, 0, stream>>>(pose, ws);
    kD<<<2048, 256, 0, stream>>>(pd, wts, ws, out);
}

// Round 4
// 125.885 us; speedup vs baseline: 1.4683x; 1.0158x over previous
//
#include <hip/hip_runtime.h>

#define NV 200000
#define NPAIR 100000
#define NK 24
#define NCH 64

// ws float offsets
#define PART_OFF 0            // 24*64*3 = 4608
#define J_OFF    4608         // 72
#define ROT_OFF  4680         // 216
#define TR_OFF   4896         // 72
#define PF_OFF   4968         // 216  (total 5184 floats = ~21 KB)

// DPP butterfly add: x += lane_permuted(x). All-VALU, no DS pipe.
// 0xB1 = quad_perm xor1   0x4E = quad_perm xor2
// 0x141 = row_half_mirror (xor4 once quads uniform)
// 0x140 = row_mirror      (xor8 once octets uniform)
template <int CTRL>
__device__ __forceinline__ float dpp_add(float x) {
    int y = __builtin_amdgcn_update_dpp(0, __float_as_int(x), CTRL, 0xf, 0xf, true);
    return x + __int_as_float(y);
}

// ---------------- kernel A: v_shaped = v_template + shapedirs . betas --------
__global__ __launch_bounds__(256) void kA(const float* __restrict__ vt,
                                          const float* __restrict__ sd,
                                          const float* __restrict__ betas,
                                          float* __restrict__ vs_out) {
    int v = blockIdx.x * 256 + threadIdx.x;
    if (v >= NV) return;
    float b[10];
#pragma unroll
    for (int i = 0; i < 10; i++) b[i] = betas[i];
    size_t v3 = 3 * (size_t)v;
    float acc0 = vt[v3], acc1 = vt[v3 + 1], acc2 = vt[v3 + 2];
    const float2* s2 = (const float2*)(sd) + (size_t)v * 15;
#pragma unroll
    for (int j = 0; j < 15; j++) {
        float2 s = s2[j];
        const int e0 = 2 * j, e1 = 2 * j + 1;
        float p0 = s.x * b[e0 % 10];
        float p1 = s.y * b[e1 % 10];
        if (e0 / 10 == 0) acc0 += p0; else if (e0 / 10 == 1) acc1 += p0; else acc2 += p0;
        if (e1 / 10 == 0) acc0 += p1; else if (e1 / 10 == 1) acc1 += p1; else acc2 += p1;
    }
    vs_out[v3] = acc0; vs_out[v3 + 1] = acc1; vs_out[v3 + 2] = acc2;
}

// ---------------- kernel B: per-(k,chunk) partial sums of J_regressor @ vs ---
__global__ __launch_bounds__(256) void kB(const float* __restrict__ jr,
                                          const float* __restrict__ vs,
                                          float* __restrict__ ws) {
    int k = blockIdx.x >> 6;
    int chunk = blockIdx.x & 63;
    const float* row = jr + (size_t)k * NV;
    float a0 = 0.f, a1 = 0.f, a2 = 0.f;
    for (int v = chunk * 256 + threadIdx.x; v < NV; v += NCH * 256) {
        float w = row[v];
        size_t v3 = 3 * (size_t)v;
        a0 = fmaf(w, vs[v3], a0);
        a1 = fmaf(w, vs[v3 + 1], a1);
        a2 = fmaf(w, vs[v3 + 2], a2);
    }
#pragma unroll
    for (int off = 32; off; off >>= 1) {
        a0 += __shfl_xor(a0, off, 64);
        a1 += __shfl_xor(a1, off, 64);
        a2 += __shfl_xor(a2, off, 64);
    }
    __shared__ float red[4][3];
    int lane = threadIdx.x & 63, wv = threadIdx.x >> 6;
    if (lane == 0) { red[wv][0] = a0; red[wv][1] = a1; red[wv][2] = a2; }
    __syncthreads();
    if (threadIdx.x < 3) {
        float s = red[0][threadIdx.x] + red[1][threadIdx.x] +
                  red[2][threadIdx.x] + red[3][threadIdx.x];
        ws[PART_OFF + blockIdx.x * 3 + threadIdx.x] = s;
    }
}

// ---------------- kernel C: J reduce, Rodrigues, depth-parallel chain --------
__global__ __launch_bounds__(64) void kC(const float* __restrict__ pose,
                                         float* __restrict__ ws) {
    __shared__ float Jl[72];
    __shared__ float Rl[24][9];
    __shared__ float Ar[24][9];
    __shared__ float At[24][3];
    int t = threadIdx.x;

    for (int idx = t; idx < 72; idx += 64) {
        int k = idx / 3, c = idx % 3;
        float s = 0.f;
#pragma unroll
        for (int ch = 0; ch < NCH; ch++) s += ws[PART_OFF + (k * NCH + ch) * 3 + c];
        Jl[idx] = s;
    }

    if (t < 24) {
        float rx = pose[3 * t], ry = pose[3 * t + 1], rz = pose[3 * t + 2];
        float tx = rx + 1e-12f, ty = ry + 1e-12f, tz = rz + 1e-12f;
        float th = sqrtf(tx * tx + ty * ty + tz * tz);
        float inv = 1.0f / th;
        float kx = rx * inv, ky = ry * inv, kz = rz * inv;
        float s = sinf(th), c = cosf(th), oc = 1.0f - c;
        float R00 = 1.f + oc * (-(ky * ky + kz * kz));
        float R01 = -s * kz + oc * kx * ky;
        float R02 =  s * ky + oc * kx * kz;
        float R10 =  s * kz + oc * kx * ky;
        float R11 = 1.f + oc * (-(kx * kx + kz * kz));
        float R12 = -s * kx + oc * ky * kz;
        float R20 = -s * ky + oc * kx * kz;
        float R21 =  s * kx + oc * ky * kz;
        float R22 = 1.f + oc * (-(kx * kx + ky * ky));
        Rl[t][0] = R00; Rl[t][1] = R01; Rl[t][2] = R02;
        Rl[t][3] = R10; Rl[t][4] = R11; Rl[t][5] = R12;
        Rl[t][6] = R20; Rl[t][7] = R21; Rl[t][8] = R22;
        float* pf = ws + PF_OFF + t * 9;
        pf[0] = R00 - 1.f; pf[1] = R01;       pf[2] = R02;
        pf[3] = R10;       pf[4] = R11 - 1.f; pf[5] = R12;
        pf[6] = R20;       pf[7] = R21;       pf[8] = R22 - 1.f;
    }
    __syncthreads();

    const int par[24] = {0,0,0,0,1,2,3,4,5,6,7,8,9,9,9,12,13,14,16,17,18,19,20,21};
    const int lvl[24] = {0,1,1,1,2,2,2,3,3,3,4,4,4,4,4,5,5,5,6,6,7,7,8,8};
    float rel0 = 0.f, rel1 = 0.f, rel2 = 0.f;
    int p = 0, myl = -1;
    if (t < 24) {
        p = par[t]; myl = lvl[t];
        if (t == 0) { rel0 = Jl[0]; rel1 = Jl[1]; rel2 = Jl[2]; }
        else {
            rel0 = Jl[3 * t]     - Jl[3 * p];
            rel1 = Jl[3 * t + 1] - Jl[3 * p + 1];
            rel2 = Jl[3 * t + 2] - Jl[3 * p + 2];
        }
    }
    for (int L = 0; L < 9; L++) {
        if (myl == L) {
            if (t == 0) {
#pragma unroll
                for (int e = 0; e < 9; e++) Ar[0][e] = Rl[0][e];
                At[0][0] = rel0; At[0][1] = rel1; At[0][2] = rel2;
            } else {
#pragma unroll
                for (int i = 0; i < 3; i++) {
                    float ai0 = Ar[p][i * 3], ai1 = Ar[p][i * 3 + 1], ai2 = Ar[p][i * 3 + 2];
#pragma unroll
                    for (int jj = 0; jj < 3; jj++) {
                        Ar[t][i * 3 + jj] = ai0 * Rl[t][jj] + ai1 * Rl[t][3 + jj] + ai2 * Rl[t][6 + jj];
                    }
                    At[t][i] = ai0 * rel0 + ai1 * rel1 + ai2 * rel2 + At[p][i];
                }
            }
        }
        __syncthreads();
    }
    if (t < 24) {
#pragma unroll
        for (int i = 0; i < 3; i++) {
            float tr = At[t][i] - (Ar[t][i * 3]     * Jl[3 * t] +
                                   Ar[t][i * 3 + 1] * Jl[3 * t + 1] +
                                   Ar[t][i * 3 + 2] * Jl[3 * t + 2]);
            ws[TR_OFF + t * 3 + i] = tr;
        }
#pragma unroll
        for (int e = 0; e < 9; e++) ws[ROT_OFF + t * 9 + e] = Ar[t][e];
    }
}

// ------- kernel D: wave-per-VERTEX-PAIR posedirs dot + half-wave skinning ----
__global__ __launch_bounds__(256) void kD(const float* __restrict__ pd,
                                          const float* __restrict__ wts,
                                          const float* __restrict__ ws,
                                          float* __restrict__ out) {
    int t = threadIdx.x;
    int l = t & 63;

    // pose_feat fragments for the 6 load offsets.
    // float4 index i = l + 64*j (j=0..5); q = (i % 162) % 54
    const float4* pf4 = (const float4*)(ws + PF_OFF);   // 54 float4
    float4 b0 = pf4[(l < 54) ? l      : l - 54];
    float4 b1 = pf4[(l < 44) ? l + 10 : l - 44];
    float4 b2 = pf4[(l < 34) ? l + 20 : l - 34];
    float4 b3 = pf4[(l < 24) ? l + 30 : l - 24];
    float4 b4 = pf4[(l < 14) ? l + 40 : l - 14];
    float4 b5 = pf4[(l <  4) ? l + 50 : 0];

    // half h handles vertex 2p+h; joint kk = l&31
    int h  = l >> 5;
    int kk = l & 31;
    float rr0=0,rr1=0,rr2=0,rr3=0,rr4=0,rr5=0,rr6=0,rr7=0,rr8=0;
    float tt0=0, tt1=0, tt2=0;
    if (kk < 24) {
        const float* r = ws + ROT_OFF + kk * 9;
        rr0=r[0]; rr1=r[1]; rr2=r[2]; rr3=r[3]; rr4=r[4];
        rr5=r[5]; rr6=r[6]; rr7=r[7]; rr8=r[8];
        const float* tr = ws + TR_OFF + kk * 3;
        tt0=tr[0]; tt1=tr[1]; tt2=tr[2];
    }

    int wid = (blockIdx.x << 2) + (t >> 6);
    int stride = gridDim.x << 2;
    for (int p = wid; p < NPAIR; p += stride) {
        const float4* base = (const float4*)(pd) + (size_t)p * 324;
        float4 A0 = base[l];
        float4 A1 = base[l + 64];
        float4 A2 = base[l + 128];
        float4 A3 = base[l + 192];
        float4 A4 = base[l + 256];
        float4 A5 = make_float4(0.f, 0.f, 0.f, 0.f);
        if (l < 4) A5 = base[l + 320];

        int vmy = 2 * p + h;
        const float* vsp = out + (size_t)vmy * 3;      // v_shaped of my vertex
        float vsx = vsp[0], vsy = vsp[1], vsz = vsp[2];
        float wk = (kk < 24) ? wts[(size_t)vmy * 24 + kk] : 0.f;

        float d0 = A0.x * b0.x + A0.y * b0.y + A0.z * b0.z + A0.w * b0.w;
        float d1 = A1.x * b1.x + A1.y * b1.y + A1.z * b1.z + A1.w * b1.w;
        float d2 = A2.x * b2.x + A2.y * b2.y + A2.z * b2.z + A2.w * b2.w;
        float d3 = A3.x * b3.x + A3.y * b3.y + A3.z * b3.z + A3.w * b3.w;
        float d4 = A4.x * b4.x + A4.y * b4.y + A4.z * b4.z + A4.w * b4.w;
        float d5 = A5.x * b5.x + A5.y * b5.y + A5.z * b5.z + A5.w * b5.w;

        // route into 6 accumulators: (v0:x,y,z, v1:x,y,z)
        float s0 = (l < 54) ? d0 : 0.f;
        float s1 = ((l < 54) ? 0.f : d0) + ((l < 44) ? d1 : 0.f);
        float s2 = ((l < 44) ? 0.f : d1) + ((l < 34) ? d2 : 0.f);
        float s3 = ((l < 34) ? 0.f : d2) + ((l < 24) ? d3 : 0.f);
        float s4 = ((l < 24) ? 0.f : d3) + ((l < 14) ? d4 : 0.f);
        float s5 = ((l < 14) ? 0.f : d4) + d5;

        // 64-lane all-reduce of 6 values: 4 DPP levels + 2 shuffle crossings
        s0 = dpp_add<0xB1>(s0); s1 = dpp_add<0xB1>(s1); s2 = dpp_add<0xB1>(s2);
        s3 = dpp_add<0xB1>(s3); s4 = dpp_add<0xB1>(s4); s5 = dpp_add<0xB1>(s5);
        s0 = dpp_add<0x4E>(s0); s1 = dpp_add<0x4E>(s1); s2 = dpp_add<0x4E>(s2);
        s3 = dpp_add<0x4E>(s3); s4 = dpp_add<0x4E>(s4); s5 = dpp_add<0x4E>(s5);
        s0 = dpp_add<0x141>(s0); s1 = dpp_add<0x141>(s1); s2 = dpp_add<0x141>(s2);
        s3 = dpp_add<0x141>(s3); s4 = dpp_add<0x141>(s4); s5 = dpp_add<0x141>(s5);
        s0 = dpp_add<0x140>(s0); s1 = dpp_add<0x140>(s1); s2 = dpp_add<0x140>(s2);
        s3 = dpp_add<0x140>(s3); s4 = dpp_add<0x140>(s4); s5 = dpp_add<0x140>(s5);
        s0 += __shfl_xor(s0, 16, 64); s1 += __shfl_xor(s1, 16, 64); s2 += __shfl_xor(s2, 16, 64);
        s3 += __shfl_xor(s3, 16, 64); s4 += __shfl_xor(s4, 16, 64); s5 += __shfl_xor(s5, 16, 64);
        s0 += __shfl_xor(s0, 32, 64); s1 += __shfl_xor(s1, 32, 64); s2 += __shfl_xor(s2, 32, 64);
        s3 += __shfl_xor(s3, 32, 64); s4 += __shfl_xor(s4, 32, 64); s5 += __shfl_xor(s5, 32, 64);

        // my vertex's v_posed (halves pick their channel sums)
        float vpx = vsx + (h ? s3 : s0);
        float vpy = vsy + (h ? s4 : s1);
        float vpz = vsz + (h ? s5 : s2);

        float m0 = wk * (rr0 * vpx + rr1 * vpy + rr2 * vpz + tt0);
        float m1 = wk * (rr3 * vpx + rr4 * vpy + rr5 * vpz + tt1);
        float m2 = wk * (rr6 * vpx + rr7 * vpy + rr8 * vpz + tt2);

        // reduce within each 32-half: 4 DPP + 1 shfl16 (no 32-crossing!)
        m0 = dpp_add<0xB1>(m0); m1 = dpp_add<0xB1>(m1); m2 = dpp_add<0xB1>(m2);
        m0 = dpp_add<0x4E>(m0); m1 = dpp_add<0x4E>(m1); m2 = dpp_add<0x4E>(m2);
        m0 = dpp_add<0x141>(m0); m1 = dpp_add<0x141>(m1); m2 = dpp_add<0x141>(m2);
        m0 = dpp_add<0x140>(m0); m1 = dpp_add<0x140>(m1); m2 = dpp_add<0x140>(m2);
        m0 += __shfl_xor(m0, 16, 64); m1 += __shfl_xor(m1, 16, 64); m2 += __shfl_xor(m2, 16, 64);

        if (kk < 3) {
            out[(size_t)vmy * 3 + kk] = (kk == 0) ? m0 : (kk == 1) ? m1 : m2;
        }
    }
}

extern "C" void kernel_launch(void* const* d_in, const int* in_sizes, int n_in,
                              void* d_out, int out_size, void* d_ws, size_t ws_size,
                              hipStream_t stream) {
    const float* betas = (const float*)d_in[0];
    const float* pose  = (const float*)d_in[1];
    const float* vt    = (const float*)d_in[2];
    const float* sd    = (const float*)d_in[3];
    const float* pd    = (const float*)d_in[4];
    const float* jr    = (const float*)d_in[5];
    const float* wts   = (const float*)d_in[6];
    float* out = (float*)d_out;
    float* ws  = (float*)d_ws;

    kA<<<(NV + 255) / 256, 256, 0, stream>>>(vt, sd, betas, out);
    kB<<<NK * NCH, 256, 0, stream>>>(jr, out, ws);
    kC<<<1, 64, 0, stream>>>(pose, ws);
    kD<<<2048, 256, 0, stream>>>(pd, wts, ws, out);
}